// Round 1
// baseline (144.538 us; speedup 1.0000x reference)
//
#include <hip/hip_runtime.h>

// Problem constants (from reference)
#define NB    8192   // batch rows
#define ND    256    // user emb dim
#define NH1   50
#define NH2   32
#define NH3   18
#define ROWS  64     // rows per block
#define KP    4      // k partitions == waves per block
#define KS    (ND / KP)   // 64 k per partition

// ws float layout: [0..17] ysum, [18..35] colsum(W_user), [36] sum(log_denom)

__device__ __forceinline__ float sigmoidf_fast(float v) {
    return 1.0f / (1.0f + __expf(-v));
}

__global__ __launch_bounds__(256) void fused_main(
    const float* __restrict__ x, const float* __restrict__ y,
    const float* __restrict__ W1, const float* __restrict__ b1,
    const float* __restrict__ W2, const float* __restrict__ b2,
    const float* __restrict__ W3, const float* __restrict__ b3,
    float* __restrict__ out, float* __restrict__ ws)
{
    // Transposed [feature][row] LDS layouts -> conflict-free lane access
    __shared__ float parts[KP - 1][NH1][ROWS];  // 3*50*64*4 = 38400 B
    __shared__ float h1buf[NH1][ROWS];          // 12800 B
    __shared__ float h2buf[NH2][ROWS];          //  8192 B

    const int t  = threadIdx.x;
    const int r  = t & 63;                                   // lane == local row
    const int kp = __builtin_amdgcn_readfirstlane(t >> 6);   // wave id, uniform
    const int row = blockIdx.x * ROWS + r;

    // ---------- Layer 1 partial: acc[j] = sum over this wave's k-slice ----------
    float acc[NH1];
#pragma unroll
    for (int j = 0; j < NH1; ++j) acc[j] = 0.0f;

    const float* xrow = x + (size_t)row * ND + kp * KS;
    const float* w1p  = W1 + (size_t)(kp * KS) * NH1;        // uniform base -> s_load

    for (int kk = 0; kk < KS; kk += 4) {
        const float4 xv = *reinterpret_cast<const float4*>(xrow + kk);
#pragma unroll
        for (int j = 0; j < NH1; ++j) {
            float a = acc[j];
            a = fmaf(xv.x, w1p[(kk + 0) * NH1 + j], a);
            a = fmaf(xv.y, w1p[(kk + 1) * NH1 + j], a);
            a = fmaf(xv.z, w1p[(kk + 2) * NH1 + j], a);
            a = fmaf(xv.w, w1p[(kk + 3) * NH1 + j], a);
            acc[j] = a;
        }
    }

    if (kp != 0) {
#pragma unroll
        for (int j = 0; j < NH1; ++j) parts[kp - 1][j][r] = acc[j];
    }
    __syncthreads();

    // ---------- Reduce partials + bias + sigmoid (wave 0) ----------
    if (kp == 0) {
#pragma unroll
        for (int j = 0; j < NH1; ++j) {
            float v = acc[j] + parts[0][j][r] + parts[1][j][r] + parts[2][j][r] + b1[j];
            h1buf[j][r] = sigmoidf_fast(v);
        }
    }
    __syncthreads();

    // ---------- Layer 2: each wave computes 8 of 32 cols for its row ----------
    {
        float h1v[NH1];
#pragma unroll
        for (int j = 0; j < NH1; ++j) h1v[j] = h1buf[j][r];
#pragma unroll
        for (int c8 = 0; c8 < 8; ++c8) {
            const int c = kp * 8 + c8;   // uniform
            float a = b2[c];
#pragma unroll
            for (int j = 0; j < NH1; ++j) a = fmaf(h1v[j], W2[j * NH2 + c], a);
            h2buf[c][r] = sigmoidf_fast(a);
        }
    }
    __syncthreads();

    // ---------- Layer 3 + epilogue (wave 0 only) ----------
    if (kp == 0) {
        float h2r[NH2];
#pragma unroll
        for (int j = 0; j < NH2; ++j) h2r[j] = h2buf[j][r];

        float wu[NH3];
#pragma unroll
        for (int c = 0; c < NH3; ++c) {
            float a = b3[c];
#pragma unroll
            for (int j = 0; j < NH2; ++j) a = fmaf(h2r[j], W3[j * NH3 + c], a);
            wu[c] = a;
        }

        // store W_user row (72 B, 8B-aligned -> float2 stores)
        float* orow = out + (size_t)row * NH3;
#pragma unroll
        for (int c = 0; c < NH3; c += 2) {
            *reinterpret_cast<float2*>(orow + c) = make_float2(wu[c], wu[c + 1]);
        }

        // factorized logsumexp over the 256 cartesian one-hot cases:
        // LSE_256 = sum over groups {[0,2),[2,6),[6,10),[10,18)} of group LSE
        float ld = 0.0f;
        {
            // group 0: len 2 @ 0
            float m = fmaxf(wu[0], wu[1]);
            float s = __expf(wu[0] - m) + __expf(wu[1] - m);
            ld += m + __logf(s);
            // group 1: len 4 @ 2
            m = fmaxf(fmaxf(wu[2], wu[3]), fmaxf(wu[4], wu[5]));
            s = __expf(wu[2] - m) + __expf(wu[3] - m) + __expf(wu[4] - m) + __expf(wu[5] - m);
            ld += m + __logf(s);
            // group 2: len 4 @ 6
            m = fmaxf(fmaxf(wu[6], wu[7]), fmaxf(wu[8], wu[9]));
            s = __expf(wu[6] - m) + __expf(wu[7] - m) + __expf(wu[8] - m) + __expf(wu[9] - m);
            ld += m + __logf(s);
            // group 3: len 8 @ 10
            m = wu[10];
#pragma unroll
            for (int i = 11; i < 18; ++i) m = fmaxf(m, wu[i]);
            s = 0.0f;
#pragma unroll
            for (int i = 10; i < 18; ++i) s += __expf(wu[i] - m);
            ld += m + __logf(s);
        }

        // y row (fused ysum reduction)
        float yv[NH3];
        const float* yrow = y + (size_t)row * NH3;
#pragma unroll
        for (int c = 0; c < NH3; ++c) yv[c] = yrow[c];

        // wave-wide reductions -> one atomicAdd per quantity per block
#pragma unroll
        for (int c = 0; c < NH3; ++c) {
            float v = wu[c];
#pragma unroll
            for (int o = 32; o >= 1; o >>= 1) v += __shfl_xor(v, o, 64);
            if (r == 0) atomicAdd(ws + 18 + c, v);       // colsum(W_user)
            float u = yv[c];
#pragma unroll
            for (int o = 32; o >= 1; o >>= 1) u += __shfl_xor(u, o, 64);
            if (r == 0) atomicAdd(ws + c, u);            // ysum
        }
        {
            float v = ld;
#pragma unroll
            for (int o = 32; o >= 1; o >>= 1) v += __shfl_xor(v, o, 64);
            if (r == 0) atomicAdd(ws + 36, v);           // sum(log_denom)
        }
    }
}

__global__ void finalize_loss(const float* __restrict__ ws, float* __restrict__ out) {
    if (threadIdx.x == 0) {
        double s = 0.0;
#pragma unroll
        for (int c = 0; c < NH3; ++c)
            s += (double)ws[18 + c] * (double)ws[c];     // colsum . ysum == sum(S)
        out[(size_t)NB * NH3] = (float)(-(s - (double)ws[36]));
    }
}

extern "C" void kernel_launch(void* const* d_in, const int* in_sizes, int n_in,
                              void* d_out, int out_size, void* d_ws, size_t ws_size,
                              hipStream_t stream) {
    const float* x  = (const float*)d_in[0];
    const float* y  = (const float*)d_in[1];
    const float* W1 = (const float*)d_in[2];
    const float* b1 = (const float*)d_in[3];
    const float* W2 = (const float*)d_in[4];
    const float* b2 = (const float*)d_in[5];
    const float* W3 = (const float*)d_in[6];
    const float* b3 = (const float*)d_in[7];
    // d_in[8] (cases) not needed: its cartesian one-hot structure is folded
    // into the factorized logsumexp in fused_main.
    float* out = (float*)d_out;
    float* ws  = (float*)d_ws;

    hipMemsetAsync(ws, 0, 37 * sizeof(float), stream);   // capture-safe
    fused_main<<<dim3(NB / ROWS), dim3(256), 0, stream>>>(x, y, W1, b1, W2, b2, W3, b3, out, ws);
    finalize_loss<<<dim3(1), dim3(64), 0, stream>>>(ws, out);
}